// Round 1
// 436.891 us; speedup vs baseline: 1.1679x; 1.1679x over previous
//
#include <hip/hip_runtime.h>
#include <math.h>

#define NPARTS 1024
#define BLOCK 256
#define WPB (BLOCK / 64)          // waves per block
#define GRID_BLOCKS 2048          // grid-stride cap (memory-bound guideline)

typedef __attribute__((ext_vector_type(4))) _Float16 half4;
typedef __attribute__((ext_vector_type(4))) float floatx4;

// Transposed-chain MFMA MLP:
//   layer L computes out^T = W_L * h^T via v_mfma_f32_16x16x16_f16.
//   A-frag  = W_L[j= lane%16][k = 4*(lane/16)+i]   (wave-uniform, loaded once)
//   B-frag  = h[m = lane%16][k = 4*(lane/16)+i]    (atom per column)
//   C/D     = out^T[row = 4*(lane/16)+r][col = lane%16]
// C/D layout == next layer's B layout (k <- row, same col), so the entire
// inter-layer step is ELU + f32->f16 convert IN REGISTERS. No LDS, no
// shuffles. x-load and out-store are single fully-coalesced dwordx4 per
// wave-tile (16 atoms = 1 KB contiguous).
__global__ __launch_bounds__(BLOCK, 8) void nodes_mlp_mfma(
    const float* __restrict__ x,       // [N,16]
    const float* __restrict__ charge,  // [1024]
    const float* __restrict__ W1, const float* __restrict__ b1,
    const float* __restrict__ W2, const float* __restrict__ b2,
    const float* __restrict__ W3, const float* __restrict__ b3,
    const int*   __restrict__ part,    // [N]
    float* __restrict__ out,           // [N,16]
    int n)
{
    __shared__ float sq[NPARTS];
    for (int i = threadIdx.x; i < NPARTS; i += BLOCK) sq[i] = charge[i];
    __syncthreads();

    const int lane = threadIdx.x & 63;
    const int col  = lane & 15;   // atom-in-tile (B/D column); W row j for A-frag
    const int g    = lane >> 4;   // k-group: frags hold k/rows 4g..4g+3

    // ---- wave-uniform fragments: A = W_L, C-init = bias (D = A*B + C) ----
    half4  aW[3];
    floatx4 cB[3];
    {
        const float* Ws[3] = {W1, W2, W3};
        const float* bs[3] = {b1, b2, b3};
#pragma unroll
        for (int L = 0; L < 3; ++L) {
            const float4 wv = *(const float4*)(Ws[L] + col * 16 + 4 * g);
            half4 a;
            a[0] = (_Float16)wv.x; a[1] = (_Float16)wv.y;
            a[2] = (_Float16)wv.z; a[3] = (_Float16)wv.w;
            aW[L] = a;
            const float4 bv = *(const float4*)(bs[L] + 4 * g);
            floatx4 c;
            c[0] = bv.x; c[1] = bv.y; c[2] = bv.z; c[3] = bv.w;
            cB[L] = c;
        }
    }

    const int ntiles = (n + 15) >> 4;
    const int nwaves = gridDim.x * WPB;

    for (int tile = blockIdx.x * WPB + (threadIdx.x >> 6);
         tile < ntiles; tile += nwaves) {

        const int row  = tile * 16 + col;          // this lane's atom
        const int rowc = (row < n) ? row : (n - 1);

        // B1-frag: x[row][4g..4g+3] — wave covers contiguous 1 KB, coalesced
        const float4 xv = *(const float4*)(x + rowc * 16 + 4 * g);
        half4 bx;
        bx[0] = (_Float16)xv.x; bx[1] = (_Float16)xv.y;
        bx[2] = (_Float16)xv.z; bx[3] = (_Float16)xv.w;

        floatx4 d = __builtin_amdgcn_mfma_f32_16x16x16f16(aW[0], bx, cB[0], 0, 0, 0);

        // ELU + cvt: D(rows 4g+r, col m) feeds next B(k=4g+i, col m) directly
        half4 h2;
#pragma unroll
        for (int i = 0; i < 4; ++i) {
            float v = d[i];
            v = (v > 0.0f) ? v : (__expf(v) - 1.0f);
            h2[i] = (_Float16)v;
        }
        d = __builtin_amdgcn_mfma_f32_16x16x16f16(aW[1], h2, cB[1], 0, 0, 0);

        half4 h3;
#pragma unroll
        for (int i = 0; i < 4; ++i) {
            float v = d[i];
            v = (v > 0.0f) ? v : (__expf(v) - 1.0f);
            h3[i] = (_Float16)v;
        }
        d = __builtin_amdgcn_mfma_f32_16x16x16f16(aW[2], h3, cB[2], 0, 0, 0);

        // final ELU stays fp32; epilogue add = part + charge[part] (fp32 exact)
        const int   p   = part[rowc];
        const float add = (float)p + sq[p];

        float4 r;
        {
            float v0 = d[0]; v0 = (v0 > 0.0f) ? v0 : (__expf(v0) - 1.0f);
            float v1 = d[1]; v1 = (v1 > 0.0f) ? v1 : (__expf(v1) - 1.0f);
            float v2 = d[2]; v2 = (v2 > 0.0f) ? v2 : (__expf(v2) - 1.0f);
            float v3 = d[3]; v3 = (v3 > 0.0f) ? v3 : (__expf(v3) - 1.0f);
            r = make_float4(v0 + add, v1 + add, v2 + add, v3 + add);
        }

        if (row < n) {
            // out[row][4g..4g+3] — same coalesced 1 KB pattern as the load
            *(float4*)(out + row * 16 + 4 * g) = r;
        }
    }
}

extern "C" void kernel_launch(void* const* d_in, const int* in_sizes, int n_in,
                              void* d_out, int out_size, void* d_ws, size_t ws_size,
                              hipStream_t stream) {
    const float* x      = (const float*)d_in[0];
    const float* charge = (const float*)d_in[1];
    const float* W1     = (const float*)d_in[2];
    const float* b1     = (const float*)d_in[3];
    const float* W2     = (const float*)d_in[4];
    const float* b2     = (const float*)d_in[5];
    const float* W3     = (const float*)d_in[6];
    const float* b3     = (const float*)d_in[7];
    const int*   part   = (const int*)d_in[8];
    float* out = (float*)d_out;

    const int n      = in_sizes[8];
    const int ntiles = (n + 15) >> 4;
    int grid = (ntiles + WPB - 1) / WPB;
    if (grid > GRID_BLOCKS) grid = GRID_BLOCKS;

    nodes_mlp_mfma<<<grid, BLOCK, 0, stream>>>(
        x, charge, W1, b1, W2, b2, W3, b3, part, out, n);
}